// Round 8
// baseline (118.895 us; speedup 1.0000x reference)
//
#include <hip/hip_runtime.h>

#define BATCH 16
#define SEQ   4096
#define DIM   64
#define WIN   512

constexpr int BM = 128;       // q rows per block
constexpr int BN = 64;        // keys per tile
constexpr int NTHREADS = 256; // 4 waves; each wave owns 32 q (one 32x32 MFMA n-group)
constexpr int KS = DIM + 4;   // Ksh row stride: 68 f16 = 136 B (8B-aligned rows)
constexpr int VS = BN + 4;    // Vsh row stride: 68 f16 = 136 B
// fold softmax scale and log2(e) into Q so p = exp2(s - m)
constexpr float QSCALE  = 0.125f * 1.44269504088896340736f;
constexpr float MASKVAL = -3.0e38f;   // << m_run init (-1e30) so masked lanes give p=0

typedef _Float16 f16x2  __attribute__((ext_vector_type(2)));
typedef _Float16 f16x4  __attribute__((ext_vector_type(4)));
typedef _Float16 f16x8  __attribute__((ext_vector_type(8)));
typedef float    f32x16 __attribute__((ext_vector_type(16)));

__device__ __forceinline__ f16x2 pk2(float a, float b) {
    return __builtin_bit_cast(f16x2, __builtin_amdgcn_cvt_pkrtz(a, b));
}
__device__ __forceinline__ int pk2i(float a, float b) {
    return __builtin_bit_cast(int, __builtin_amdgcn_cvt_pkrtz(a, b));
}
// 8 f16 from two 8B-aligned LDS reads
__device__ __forceinline__ f16x8 ld8(const _Float16* p) {
    union { f16x8 v; f16x4 h[2]; } u;
    u.h[0] = *(const f16x4*)p;
    u.h[1] = *(const f16x4*)(p + 4);
    return u.v;
}

__device__ __forceinline__ void stage_kv(_Float16* __restrict__ Ksh, _Float16* __restrict__ Vsh,
                                         const float4* kvv, const float4* vvv,
                                         int krow, int dbase) {
    #pragma unroll
    for (int s = 0; s < 4; ++s) {
        union { f16x4 v; f16x2 h[2]; } uk;
        uk.h[0] = pk2(kvv[s].x, kvv[s].y);
        uk.h[1] = pk2(kvv[s].z, kvv[s].w);
        *(f16x4*)&Ksh[krow * KS + dbase + 4 * s] = uk.v;
        // transposed V: one wave-instr per (s,j) hits all 32 banks 2-way (free)
        Vsh[(dbase + 4 * s + 0) * VS + krow] = (_Float16)vvv[s].x;
        Vsh[(dbase + 4 * s + 1) * VS + krow] = (_Float16)vvv[s].y;
        Vsh[(dbase + 4 * s + 2) * VS + krow] = (_Float16)vvv[s].z;
        Vsh[(dbase + 4 * s + 3) * VS + krow] = (_Float16)vvv[s].w;
    }
}

__global__ __launch_bounds__(NTHREADS)
void swa_kernel(const float* __restrict__ qg, const float* __restrict__ kg,
                const float* __restrict__ vg, float* __restrict__ outg) {
    // Ksh [BN][KS] f16 (8704 B) | Vsh [DIM][VS] f16 (8704 B) = 17408 B
    __shared__ __align__(16) char smem[(BN * KS + DIM * VS) * 2];
    _Float16* Ksh = (_Float16*)smem;
    _Float16* Vsh = (_Float16*)(smem + BN * KS * 2);

    const int tid  = threadIdx.x;
    const int lane = tid & 63;
    const int wave = tid >> 6;     // 0..3
    const int ql   = lane & 31;    // q within wave's 32-group / m within mtile
    const int h    = lane >> 5;    // half-wave

    const int b     = blockIdx.y;
    const int qblk  = blockIdx.x;
    const int qrow0 = qblk * BM;
    const int wq0   = qrow0 + wave * 32;  // wave's first q
    const int q     = wq0 + ql;           // this lane's q column

    const float* qb = qg + (size_t)b * SEQ * DIM;
    const float* kb = kg + (size_t)b * SEQ * DIM;
    const float* vb = vg + (size_t)b * SEQ * DIM;
    float*       ob = outg + (size_t)b * SEQ * DIM;

    // staging map: lane = key row (0..63), wave stages d-columns [16w, 16w+16)
    const int krow  = lane;
    const int dbase = wave * 16;

    // ---- Q B-frags: lane holds Q[q][kc*16 + h*8 + j], j=0..7, per k-chunk kc ----
    f16x8 qf[4];
    #pragma unroll
    for (int kc = 0; kc < 4; ++kc) {
        const float* qp = qb + (size_t)q * DIM + kc * 16 + h * 8;
        const float4 x = *(const float4*)(qp + 0);
        const float4 y = *(const float4*)(qp + 4);
        union { f16x8 v; f16x2 p[4]; } u;
        u.p[0] = pk2(x.x * QSCALE, x.y * QSCALE);
        u.p[1] = pk2(x.z * QSCALE, x.w * QSCALE);
        u.p[2] = pk2(y.x * QSCALE, y.y * QSCALE);
        u.p[3] = pk2(y.z * QSCALE, y.w * QSCALE);
        qf[kc] = u.v;
    }

    f32x16 o0 = (f32x16)(0.f), o1 = (f32x16)(0.f);
    float m_run = -1e30f, l_run = 0.f;

    const int t0 = (qrow0 > (WIN - 1)) ? (qrow0 - (WIN - 1)) >> 6 : 0;
    const int t1 = (qrow0 + BM - 1) >> 6;

    // ---- prologue: stage tile t0 (each lane reads its own 64B line) ----
    {
        float4 kv[4], vv[4];
        const float* kp = kb + (size_t)(t0 * BN + krow) * DIM + dbase;
        const float* vp = vb + (size_t)(t0 * BN + krow) * DIM + dbase;
        #pragma unroll
        for (int s = 0; s < 4; ++s) {
            kv[s] = *(const float4*)(kp + 4 * s);
            vv[s] = *(const float4*)(vp + 4 * s);
        }
        stage_kv(Ksh, Vsh, kv, vv, krow, dbase);
    }
    __syncthreads();

    for (int t = t0; t <= t1; ++t) {
        const bool have_next = (t < t1);
        float4 kpre[4], vpre[4];
        if (have_next) {
            // in flight across compute; consumed after the raw barrier (no vmcnt(0) drain)
            const float* kp = kb + (size_t)((t + 1) * BN + krow) * DIM + dbase;
            const float* vp = vb + (size_t)((t + 1) * BN + krow) * DIM + dbase;
            #pragma unroll
            for (int s = 0; s < 4; ++s) {
                kpre[s] = *(const float4*)(kp + 4 * s);
                vpre[s] = *(const float4*)(vp + 4 * s);
            }
        }

        const int kbase = t * BN;
        const bool active = (kbase <= wq0 + 31) && (kbase + BN - 1 >= wq0 - (WIN - 1));
        if (active) {
            // ---- S^T = K * Q^T : 2 key m-tiles x 4 k-chunks of 16 ----
            f32x16 s0 = (f32x16)(0.f), s1 = (f32x16)(0.f);
            #pragma unroll
            for (int kc = 0; kc < 4; ++kc) {
                const int off = kc * 16 + h * 8;
                const f16x8 a0 = ld8(&Ksh[(ql) * KS + off]);
                const f16x8 a1 = ld8(&Ksh[(32 + ql) * KS + off]);
                s0 = __builtin_amdgcn_mfma_f32_32x32x16_f16(a0, qf[kc], s0, 0, 0, 0);
                s1 = __builtin_amdgcn_mfma_f32_32x32x16_f16(a1, qf[kc], s1, 0, 0, 0);
            }

            // ---- mask on window-edge tiles only (wave-uniform) ----
            // C-layout row (key within mtile) = (r&3) + 8*(r>>2) + 4*h
            const bool edge = (kbase < wq0 + 31 - (WIN - 1)) || (kbase + BN - 1 > wq0);
            if (edge) {
                #pragma unroll
                for (int r = 0; r < 16; ++r) {
                    const int k0 = kbase + (r & 3) + 8 * (r >> 2) + 4 * h;
                    s0[r] = ((unsigned)(q - k0) < (unsigned)WIN) ? s0[r] : MASKVAL;
                    const int k1 = k0 + 32;
                    s1[r] = ((unsigned)(q - k1) < (unsigned)WIN) ? s1[r] : MASKVAL;
                }
            }

            // ---- online softmax: lane owns one q; lane^32 holds the other 32 keys ----
            float mt_ = MASKVAL;
            #pragma unroll
            for (int r = 0; r < 16; ++r) mt_ = fmaxf(mt_, fmaxf(s0[r], s1[r]));
            mt_ = fmaxf(mt_, __shfl_xor(mt_, 32));
            const float mn    = fmaxf(m_run, mt_);
            const float alpha = exp2f(m_run - mn);
            m_run = mn;

            f32x16 p0, p1;
            float ls = 0.f;
            #pragma unroll
            for (int r = 0; r < 16; ++r) {
                p0[r] = exp2f(s0[r] - mn);
                p1[r] = exp2f(s1[r] - mn);
                ls += p0[r] + p1[r];
            }
            l_run = l_run * alpha + ls;
            #pragma unroll
            for (int r = 0; r < 16; ++r) { o0[r] *= alpha; o1[r] *= alpha; }

            // ---- O^T += V^T * P^T (32x32x16; B-frag built from C-layout regs) ----
            #pragma unroll
            for (int kc = 0; kc < 4; ++kc) {
                const f32x16 pm = (kc < 2) ? p0 : p1;
                const int base = 8 * (kc & 1);   // reg groups 2(kc&1), 2(kc&1)+1
                const int A0 = pk2i(pm[base + 0], pm[base + 1]);
                const int A1 = pk2i(pm[base + 2], pm[base + 3]);
                const int B0 = pk2i(pm[base + 4], pm[base + 5]);
                const int B1 = pk2i(pm[base + 6], pm[base + 7]);
                // h=0 frag = [ownA, partnerA]; h=1 frag = [partnerB, ownB]
                const int s0_ = h ? A0 : B0;          // what partner needs
                const int s1_ = h ? A1 : B1;
                const int r0 = __shfl_xor(s0_, 32);
                const int r1 = __shfl_xor(s1_, 32);
                union { f16x8 v; int i[4]; } pb;
                pb.i[0] = h ? r0 : A0;
                pb.i[1] = h ? r1 : A1;
                pb.i[2] = h ? B0 : r0;
                pb.i[3] = h ? B1 : r1;
                const int off = kc * 16 + h * 8;
                const f16x8 vf0 = ld8(&Vsh[(ql) * VS + off]);
                const f16x8 vf1 = ld8(&Vsh[(32 + ql) * VS + off]);
                o0 = __builtin_amdgcn_mfma_f32_32x32x16_f16(vf0, pb.v, o0, 0, 0, 0);
                o1 = __builtin_amdgcn_mfma_f32_32x32x16_f16(vf1, pb.v, o1, 0, 0, 0);
            }
        }

        // raw barrier: LDS reads/permutes already consumed (lgkmcnt precedes MFMA use);
        // prefetch globals stay in flight -> must NOT use __syncthreads here
        __builtin_amdgcn_s_barrier();
        if (have_next) {
            stage_kv(Ksh, Vsh, kpre, vpre, krow, dbase);
        }
        __syncthreads();   // ds_writes visible; prefetch already consumed
    }

    // ---- epilogue: l across half-waves, normalize, direct float4 stores ----
    l_run += __shfl_xor(l_run, 32);
    const float inv = 1.0f / l_run;
    #pragma unroll
    for (int mt = 0; mt < 2; ++mt) {
        const f32x16 ov = mt ? o1 : o0;
        #pragma unroll
        for (int g = 0; g < 4; ++g) {
            const int d = mt * 32 + 8 * g + 4 * h;   // rows 4g..4g+3 are d..d+3
            float4 st;
            st.x = ov[4 * g + 0] * inv;
            st.y = ov[4 * g + 1] * inv;
            st.z = ov[4 * g + 2] * inv;
            st.w = ov[4 * g + 3] * inv;
            *(float4*)&ob[(size_t)q * DIM + d] = st;
        }
    }
}

extern "C" void kernel_launch(void* const* d_in, const int* in_sizes, int n_in,
                              void* d_out, int out_size, void* d_ws, size_t ws_size,
                              hipStream_t stream) {
    (void)in_sizes; (void)n_in; (void)out_size; (void)d_ws; (void)ws_size;
    const float* q = (const float*)d_in[0];
    const float* k = (const float*)d_in[1];
    const float* v = (const float*)d_in[2];
    float* out = (float*)d_out;
    dim3 grid(SEQ / BM, BATCH);
    swa_kernel<<<grid, dim3(NTHREADS), 0, stream>>>(q, k, v, out);
}

// Round 9
// 110.532 us; speedup vs baseline: 1.0757x; 1.0757x over previous
//
#include <hip/hip_runtime.h>

#define BATCH 16
#define SEQ   4096
#define DIM   64
#define WIN   512

constexpr int BM = 128;       // q rows per block
constexpr int BN = 64;        // keys per tile
constexpr int NTHREADS = 512; // 8 waves; each wave owns 16 q rows (proven R4 body)
// LDS: KS=VS=64, no pad; conflicts killed by XOR swizzle instead.
// K[row][d]: 16B chunks, chunk' = (d/8) ^ (row&7)
// V[d][key]: 8B chunks,  j'     = (key/4) ^ (d&15)
// fold softmax scale and log2(e) into Q so p = exp2(s - m)
constexpr float QSCALE  = 0.125f * 1.44269504088896340736f;
constexpr float MASKVAL = -3.0e38f;   // << m_run init (-1e30) so masked lanes give p=0

typedef _Float16 f16x2 __attribute__((ext_vector_type(2)));
typedef _Float16 f16x4 __attribute__((ext_vector_type(4)));
typedef _Float16 f16x8 __attribute__((ext_vector_type(8)));
typedef float    f32x4 __attribute__((ext_vector_type(4)));

__device__ __forceinline__ f16x2 pk2(float a, float b) {
    return __builtin_bit_cast(f16x2, __builtin_amdgcn_cvt_pkrtz(a, b));
}

// stage one K row-chunk (row krow, d in [8w,8w+8)) and transposed V
__device__ __forceinline__ void stage_kv(_Float16* __restrict__ Ksh, _Float16* __restrict__ Vsh,
                                         const float4* kv, const float4* vv,
                                         int krow, int w) {
    union { f16x8 v; f16x2 h[4]; } uk;
    uk.h[0] = pk2(kv[0].x, kv[0].y);
    uk.h[1] = pk2(kv[0].z, kv[0].w);
    uk.h[2] = pk2(kv[1].x, kv[1].y);
    uk.h[3] = pk2(kv[1].z, kv[1].w);
    *(f16x8*)&Ksh[krow * 64 + ((w ^ (krow & 7)) * 8)] = uk.v;   // b128, uniform banks
    const int jb = krow >> 2, e = krow & 3;
    #pragma unroll
    for (int s = 0; s < 2; ++s) {
        const float* vf = (const float*)&vv[s];
        #pragma unroll
        for (int j = 0; j < 4; ++j) {
            const int d = 8 * w + 4 * s + j;
            Vsh[d * 64 + ((jb ^ (d & 15)) * 4) + e] = (_Float16)vf[j];  // 2-way = free
        }
    }
}

__global__ __launch_bounds__(NTHREADS)
void swa_kernel(const float* __restrict__ qg, const float* __restrict__ kg,
                const float* __restrict__ vg, float* __restrict__ outg) {
    __shared__ __align__(16) _Float16 Ksh[BN * 64];   // 8 KB
    __shared__ __align__(16) _Float16 Vsh[DIM * 64];  // 8 KB

    const int tid  = threadIdx.x;
    const int lane = tid & 63;
    const int wave = tid >> 6;     // 0..7
    const int lr   = lane & 15;
    const int quad = lane >> 4;

    const int b     = blockIdx.y;
    const int qblk  = blockIdx.x;
    const int qrow0 = qblk * BM;
    const int wr0   = qrow0 + wave * 16;  // wave's first q row
    const int q     = wr0 + lr;           // this lane's q column (S^T layout)

    const float* qb = qg + (size_t)b * SEQ * DIM;
    const float* kb = kg + (size_t)b * SEQ * DIM;
    const float* vb = vg + (size_t)b * SEQ * DIM;
    float*       ob = outg + (size_t)b * SEQ * DIM;

    // staging map: lane = key row (0..63); wave w stages d-columns [8w, 8w+8)
    const int krow = lane;

    // ---- Q B-frags straight from global into registers ----
    const float* qp = qb + (size_t)q * DIM + quad * 8;
    const float4 a0 = *(const float4*)(qp + 0);
    const float4 a1 = *(const float4*)(qp + 4);
    const float4 a2 = *(const float4*)(qp + 32);
    const float4 a3 = *(const float4*)(qp + 36);
    union { f16x8 v; f16x2 h[4]; } uq0, uq1;
    uq0.h[0] = pk2(a0.x * QSCALE, a0.y * QSCALE);
    uq0.h[1] = pk2(a0.z * QSCALE, a0.w * QSCALE);
    uq0.h[2] = pk2(a1.x * QSCALE, a1.y * QSCALE);
    uq0.h[3] = pk2(a1.z * QSCALE, a1.w * QSCALE);
    uq1.h[0] = pk2(a2.x * QSCALE, a2.y * QSCALE);
    uq1.h[1] = pk2(a2.z * QSCALE, a2.w * QSCALE);
    uq1.h[2] = pk2(a3.x * QSCALE, a3.y * QSCALE);
    uq1.h[3] = pk2(a3.z * QSCALE, a3.w * QSCALE);
    const f16x8 qf0 = uq0.v, qf1 = uq1.v;

    f32x4 o[4];
    #pragma unroll
    for (int mi = 0; mi < 4; ++mi) o[mi] = (f32x4){0.f, 0.f, 0.f, 0.f};
    float m_run = -1e30f, l_run = 0.f;

    const int t0 = (qrow0 > (WIN - 1)) ? (qrow0 - (WIN - 1)) >> 6 : 0;
    const int t1 = (qrow0 + BM - 1) >> 6;

    // ---- prologue: stage tile t0 directly ----
    {
        float4 kv[2], vv[2];
        const float* kp = kb + (size_t)(t0 * BN + krow) * DIM + 8 * wave;
        const float* vp = vb + (size_t)(t0 * BN + krow) * DIM + 8 * wave;
        kv[0] = *(const float4*)(kp + 0);
        kv[1] = *(const float4*)(kp + 4);
        vv[0] = *(const float4*)(vp + 0);
        vv[1] = *(const float4*)(vp + 4);
        stage_kv(Ksh, Vsh, kv, vv, krow, wave);
    }
    __syncthreads();

    for (int t = t0; t <= t1; ++t) {
        const bool have_next = (t < t1);
        float4 kpre[2], vpre[2];
        if (have_next) {
            // issue next tile's global loads NOW; consumed after the raw barrier,
            // so they stay in flight across compute (no vmcnt(0) drain)
            const float* kp = kb + (size_t)((t + 1) * BN + krow) * DIM + 8 * wave;
            const float* vp = vb + (size_t)((t + 1) * BN + krow) * DIM + 8 * wave;
            kpre[0] = *(const float4*)(kp + 0);
            kpre[1] = *(const float4*)(kp + 4);
            vpre[0] = *(const float4*)(vp + 0);
            vpre[1] = *(const float4*)(vp + 4);
        }

        const int kbase = t * BN;
        // wave-level skip: no key of this tile is inside this wave's window
        const bool active = (kbase + BN - 1 >= wr0 - (WIN - 1)) && (kbase <= wr0 + 15);
        if (active) {
            // ---- S^T = K * Q^T : 4 key m-tiles x 2 k-chunks of 32 ----
            f32x4 sc[4];
            #pragma unroll
            for (int mt = 0; mt < 4; ++mt) {
                const int row = mt * 16 + lr;
                const f16x8 kf0 = *(const f16x8*)&Ksh[row * 64 + ((quad       ^ (lr & 7)) * 8)];
                const f16x8 kf1 = *(const f16x8*)&Ksh[row * 64 + (((4 | quad) ^ (lr & 7)) * 8)];
                f32x4 s = (f32x4){0.f, 0.f, 0.f, 0.f};
                s = __builtin_amdgcn_mfma_f32_16x16x32_f16(kf0, qf0, s, 0, 0, 0);
                s = __builtin_amdgcn_mfma_f32_16x16x32_f16(kf1, qf1, s, 0, 0, 0);
                sc[mt] = s;
            }

            // ---- mask only on window-edge tiles (wave-uniform branch) ----
            const bool edge = (kbase < wr0 + 15 - (WIN - 1)) || (kbase + BN - 1 > wr0);
            if (edge) {
                #pragma unroll
                for (int mt = 0; mt < 4; ++mt) {
                    #pragma unroll
                    for (int r = 0; r < 4; ++r) {
                        const int key = kbase + mt * 16 + quad * 4 + r;
                        sc[mt][r] = ((unsigned)(q - key) < (unsigned)WIN) ? sc[mt][r] : MASKVAL;
                    }
                }
            }

            // ---- online softmax (one q per lane) ----
            float mt_ = MASKVAL;
            #pragma unroll
            for (int mtile = 0; mtile < 4; ++mtile)
                #pragma unroll
                for (int r = 0; r < 4; ++r) mt_ = fmaxf(mt_, sc[mtile][r]);
            mt_ = fmaxf(mt_, __shfl_xor(mt_, 16));
            mt_ = fmaxf(mt_, __shfl_xor(mt_, 32));
            const float mn    = fmaxf(m_run, mt_);
            const float alpha = exp2f(m_run - mn);
            m_run = mn;

            f16x4 pb[4];
            float ls = 0.f;
            #pragma unroll
            for (int nt = 0; nt < 4; ++nt) {
                const float p0 = exp2f(sc[nt][0] - mn);
                const float p1 = exp2f(sc[nt][1] - mn);
                const float p2 = exp2f(sc[nt][2] - mn);
                const float p3 = exp2f(sc[nt][3] - mn);
                ls += (p0 + p1) + (p2 + p3);
                union { f16x4 v; f16x2 h[2]; } up;
                up.h[0] = pk2(p0, p1);
                up.h[1] = pk2(p2, p3);
                pb[nt] = up.v;
            }
            l_run = l_run * alpha + ls;
            #pragma unroll
            for (int mi = 0; mi < 4; ++mi) o[mi] = o[mi] * alpha;

            // ---- O^T += V^T * P^T : P^T (C-layout) is the B-operand of 16x16x16 ----
            #pragma unroll
            for (int nt = 0; nt < 4; ++nt) {
                #pragma unroll
                for (int mi = 0; mi < 4; ++mi) {
                    const int d = mi * 16 + lr;
                    const f16x4 vf = *(const f16x4*)&Vsh[d * 64 + (((4 * nt + quad) ^ lr) * 4)];
                    o[mi] = __builtin_amdgcn_mfma_f32_16x16x16f16(vf, pb[nt], o[mi], 0, 0, 0);
                }
            }
        }

        // raw barrier: LDS read results already consumed (lgkmcnt waits precede MFMA
        // use); prefetch global loads must NOT be drained here -> no __syncthreads
        __builtin_amdgcn_s_barrier();
        if (have_next) {
            stage_kv(Ksh, Vsh, kpre, vpre, krow, wave);
        }
        __syncthreads();   // ds_writes visible; prefetch already consumed, no extra drain
    }

    // ---- epilogue: l reduce across quads, normalize, direct float4 stores ----
    // O^T C-layout: lane (lr,quad) holds O[d = mi*16 + quad*4 + r][q] contiguous in d.
    l_run += __shfl_xor(l_run, 16);
    l_run += __shfl_xor(l_run, 32);
    const float inv = 1.0f / l_run;
    #pragma unroll
    for (int mi = 0; mi < 4; ++mi) {
        float4 st;
        st.x = o[mi][0] * inv; st.y = o[mi][1] * inv;
        st.z = o[mi][2] * inv; st.w = o[mi][3] * inv;
        *(float4*)&ob[(size_t)q * DIM + mi * 16 + quad * 4] = st;
    }
}

extern "C" void kernel_launch(void* const* d_in, const int* in_sizes, int n_in,
                              void* d_out, int out_size, void* d_ws, size_t ws_size,
                              hipStream_t stream) {
    (void)in_sizes; (void)n_in; (void)out_size; (void)d_ws; (void)ws_size;
    const float* q = (const float*)d_in[0];
    const float* k = (const float*)d_in[1];
    const float* v = (const float*)d_in[2];
    float* out = (float*)d_out;
    dim3 grid(SEQ / BM, BATCH);
    swa_kernel<<<grid, dim3(NTHREADS), 0, stream>>>(q, k, v, out);
}